// Round 5
// baseline (310.825 us; speedup 1.0000x reference)
//
#include <hip/hip_runtime.h>

#define DEVI __device__ __forceinline__

constexpr int S = 8192, D = 1024, H = 16, HD = 64;
constexpr int NQKV = 3 * D;

typedef __attribute__((ext_vector_type(8))) __bf16 bf16x8;
typedef __attribute__((ext_vector_type(4))) __bf16 bf16x4;
typedef __attribute__((ext_vector_type(8))) unsigned short us8;
typedef __attribute__((ext_vector_type(4))) float f32x4;

DEVI unsigned short f2b(float f) {
  unsigned int u = __float_as_uint(f);
  u += 0x7fff + ((u >> 16) & 1);   // RNE
  return (unsigned short)(u >> 16);
}

DEVI ushort4 cvt4(float4 v) {
  ushort4 r; r.x = f2b(v.x); r.y = f2b(v.y); r.z = f2b(v.z); r.w = f2b(v.w); return r;
}

DEVI void load_lds16b(const void* g, void* l) {
  __builtin_amdgcn_global_load_lds((const __attribute__((address_space(1))) void*)g,
                                   (__attribute__((address_space(3))) void*)l,
                                   16, 0, 0);
}

// ---------------- prep: fp32 -> bf16 casts + weight/bias concat ----------------
__global__ void prep_kernel(const float4* __restrict__ x,
                            const float4* __restrict__ Wq, const float4* __restrict__ Wk,
                            const float4* __restrict__ Wv, const float4* __restrict__ Wo,
                            const float4* __restrict__ bq, const float4* __restrict__ bk,
                            const float4* __restrict__ bv,
                            ushort4* __restrict__ xb, ushort4* __restrict__ wqkv,
                            ushort4* __restrict__ wob, float4* __restrict__ biasq)
{
  constexpr int NX = S * D / 4;
  constexpr int NW = D * D / 4;
  constexpr int NB = D / 4;
  constexpr int TOT = NX + 4 * NW + 3 * NB;
  for (int i = blockIdx.x * blockDim.x + threadIdx.x; i < TOT; i += gridDim.x * blockDim.x) {
    if (i < NX) {
      xb[i] = cvt4(x[i]);
    } else if (i < NX + 3 * NW) {
      int j = i - NX;
      const float4* src = (j < NW) ? Wq : ((j < 2 * NW) ? Wk : Wv);
      int jj = (j < NW) ? j : ((j < 2 * NW) ? j - NW : j - 2 * NW);
      wqkv[j] = cvt4(src[jj]);
    } else if (i < NX + 4 * NW) {
      int j = i - NX - 3 * NW;
      wob[j] = cvt4(Wo[j]);
    } else {
      int j = i - NX - 4 * NW;
      const float4* src = (j < NB) ? bq : ((j < 2 * NB) ? bk : bv);
      int jj = (j < NB) ? j : ((j < 2 * NB) ? j - NB : j - 2 * NB);
      biasq[j] = src[jj];
    }
  }
}

// ---------------- NT GEMM: C[m][n] = sum_k A[m][k]*B[n][k] + bias[n] ----------------
template<int LDC, bool OUT_BF16>
__global__ __launch_bounds__(256)
void gemm_nt(const unsigned short* __restrict__ A,
             const unsigned short* __restrict__ B,
             const float* __restrict__ bias,
             void* __restrict__ C, int K)
{
  __shared__ __align__(16) unsigned short As[128 * 32];
  __shared__ __align__(16) unsigned short Bs[128 * 32];
  const int tid = threadIdx.x;
  const int wave = tid >> 6, lane = tid & 63;
  const int quad = lane >> 4, l15 = lane & 15;
  const int m0 = blockIdx.x * 128, n0 = blockIdx.y * 128;
  const int wr = wave >> 1, wc = wave & 1;

  const f32x4 fzero = {0.f, 0.f, 0.f, 0.f};
  f32x4 acc[4][4];
#pragma unroll
  for (int i = 0; i < 4; ++i)
#pragma unroll
    for (int j = 0; j < 4; ++j) acc[i][j] = fzero;

  const int segr = lane >> 2;
  const int cpst = lane & 3;

  for (int k0 = 0; k0 < K; k0 += 32) {
    __syncthreads();
#pragma unroll
    for (int j = 0; j < 4; ++j) {
      const int s = wave * 4 + j;
      const int s7 = s & 7;
      const int r = s7 * 16 + segr;
      const int c = cpst ^ ((r >> 1) & 3);
      const unsigned short* g = (s < 8)
        ? A + (size_t)(m0 + r) * K + k0 + c * 8
        : B + (size_t)(n0 + r) * K + k0 + c * 8;
      unsigned short* l = ((s < 8) ? As : Bs) + s7 * 512;
      load_lds16b(g, l);
    }
    __syncthreads();

    bf16x8 af[4], bfr[4];
#pragma unroll
    for (int it = 0; it < 4; ++it) {
      const int r = wr * 64 + it * 16 + l15;
      const int cp = quad ^ ((r >> 1) & 3);
      af[it] = *(const bf16x8*)&As[r * 32 + cp * 8];
    }
#pragma unroll
    for (int jt = 0; jt < 4; ++jt) {
      const int r = wc * 64 + jt * 16 + l15;
      const int cp = quad ^ ((r >> 1) & 3);
      bfr[jt] = *(const bf16x8*)&Bs[r * 32 + cp * 8];
    }
#pragma unroll
    for (int it = 0; it < 4; ++it)
#pragma unroll
      for (int jt = 0; jt < 4; ++jt)
        acc[it][jt] = __builtin_amdgcn_mfma_f32_16x16x32_bf16(af[it], bfr[jt], acc[it][jt], 0, 0, 0);
  }

#pragma unroll
  for (int it = 0; it < 4; ++it)
#pragma unroll
    for (int jt = 0; jt < 4; ++jt) {
      const int col = n0 + wc * 64 + jt * 16 + l15;
      const float bv = bias[col];
#pragma unroll
      for (int i = 0; i < 4; ++i) {
        const int row = m0 + wr * 64 + it * 16 + quad * 4 + i;
        const float v = acc[it][jt][i] + bv;
        if constexpr (OUT_BF16)
          ((unsigned short*)C)[(size_t)row * LDC + col] = f2b(v);
        else
          ((float*)C)[(size_t)row * LDC + col] = v;
      }
    }
}

// ---------------- fused sliding-window attention (v4) ----------------
// S^T = mfma(K,Q): lane holds 4 CONSECUTIVE keys per query -> P written as one
// ds_write_b64 (packed cvt), l is one scalar/rt. K frags loaded straight from
// global (no Ks LDS -> 23.5 KB LDS -> 6 blocks/CU). V^T double-buffered via
// reg scatter, one barrier/iter. exp2-folded no-max softmax (v_exp_f32).
__global__ __launch_bounds__(256)
void attn_fused(const unsigned short* __restrict__ qkv,
                unsigned short* __restrict__ attnb)
{
  __shared__ __align__(16) unsigned short Vt[2][64 * 72];  // [d][(kc^(d>>3))*8 + (key&7)]
  __shared__ __align__(16) unsigned short Ps[4][16 * 40];  // per-wave P, [q][key], pitch 40
  const int tid = threadIdx.x;
  const int wave = tid >> 6, lane = tid & 63;
  const int quad = lane >> 4, l15 = lane & 15;
  const int h = blockIdx.y;
  const int q0 = blockIdx.x * 128;
  const int wq0 = q0 + wave * 32;

  const unsigned short* Qp = qkv + h * HD;
  const unsigned short* Kp = qkv + D + h * HD;
  const unsigned short* Vp = qkv + 2 * D + h * HD;

  bf16x8 qf[2][2];
#pragma unroll
  for (int rt = 0; rt < 2; ++rt)
#pragma unroll
    for (int ksp = 0; ksp < 2; ++ksp)
      qf[rt][ksp] = *(const bf16x8*)(Qp + (size_t)(wq0 + rt * 16 + l15) * NQKV + ksp * 32 + quad * 8);

  const f32x4 fzero = {0.f, 0.f, 0.f, 0.f};
  f32x4 o[2][4];
  float lr[2] = {0.f, 0.f};
#pragma unroll
  for (int rt = 0; rt < 2; ++rt)
#pragma unroll
    for (int vt = 0; vt < 4; ++vt) o[rt][vt] = fzero;

  const int ks = (q0 >= 512) ? (q0 - 512) : 0;
  const int ke = (q0 + 640 < S) ? (q0 + 640) : S;

  const int skey = tid >> 3;            // 0..31
  const int sg   = tid & 7;             // dim-chunk group

  us8 vreg[2];

#define LOAD_V(kt_)                                                               \
  {                                                                               \
    _Pragma("unroll")                                                             \
    for (int r = 0; r < 2; ++r)                                                   \
      vreg[r] = *(const us8*)(Vp + (size_t)((kt_) + skey + r * 32) * NQKV + sg * 8); \
  }
#define SCAT_V(b_)                                                                \
  {                                                                               \
    _Pragma("unroll")                                                             \
    for (int r = 0; r < 2; ++r) {                                                 \
      const int key = skey + r * 32;                                              \
      const int ch = (key >> 3) ^ sg;                                             \
      unsigned short* dst = &Vt[b_][sg * 8 * 72 + ch * 8 + (key & 7)];            \
      _Pragma("unroll")                                                           \
      for (int j = 0; j < 8; ++j) dst[j * 72] = vreg[r][j];                       \
    }                                                                             \
  }

  LOAD_V(ks);
  SCAT_V(0);

  constexpr float L2E8 = 0.18033688011112042f;  // log2(e)/8

  int b = 0;
  for (int kt = ks; kt < ke; kt += 64, b ^= 1) {
    __syncthreads();                       // Vt[b] staged by all waves
    const int nx = kt + 64;
    const bool more = (nx < ke);
    if (more) LOAD_V(nx);                  // global V loads overlap compute

    if (kt + 63 >= wq0 - 512 && kt <= wq0 + 542) {
      unsigned short* Pw = (unsigned short*)Ps[wave];
#pragma unroll
      for (int st = 0; st < 2; ++st) {
        const int C0 = kt + st * 32;
        if (!((C0 + 31 >= wq0 - 512) && (C0 <= wq0 + 542))) continue;

        bf16x8 kf[2][2];
#pragma unroll
        for (int hh2 = 0; hh2 < 2; ++hh2)
#pragma unroll
          for (int ksp = 0; ksp < 2; ++ksp)
            kf[hh2][ksp] = *(const bf16x8*)(Kp + (size_t)(C0 + hh2 * 16 + l15) * NQKV
                                            + ksp * 32 + quad * 8);
        bf16x8 vf[4];
#pragma unroll
        for (int vt = 0; vt < 4; ++vt) {
          const int d = vt * 16 + l15;
          vf[vt] = *(const bf16x8*)&Vt[b][d * 72 + (((st * 4 + quad) ^ (d >> 3)) & 7) * 8];
        }

#pragma unroll
        for (int rt = 0; rt < 2; ++rt) {
          const int R = wq0 + rt * 16;
          if (!((C0 + 31 >= R - 512) && (C0 <= R + 526))) continue;
          const int qa = R + l15;          // this lane's query

#pragma unroll
          for (int hh2 = 0; hh2 < 2; ++hh2) {
            const int C = C0 + hh2 * 16;
            const bool any  = (C + 15 >= R - 512) && (C <= R + 526);
            const bool full = (C >= R - 497) && (C <= R + 496);
            float p[4];
            if (!any) {
              p[0] = p[1] = p[2] = p[3] = 0.f;
            } else {
              // S^T tile: rows = keys (quad*4+i), cols = queries (l15)
              f32x4 z = fzero;
              z = __builtin_amdgcn_mfma_f32_16x16x32_bf16(kf[hh2][0], qf[rt][0], z, 0, 0, 0);
              z = __builtin_amdgcn_mfma_f32_16x16x32_bf16(kf[hh2][1], qf[rt][1], z, 0, 0, 0);
              if (full) {
#pragma unroll
                for (int i = 0; i < 4; ++i) p[i] = __builtin_amdgcn_exp2f(z[i] * L2E8);
              } else {
                const int base = C + quad * 4 - qa + 512;
#pragma unroll
                for (int i = 0; i < 4; ++i)
                  p[i] = ((unsigned)(base + i) < 1024u) ? __builtin_amdgcn_exp2f(z[i] * L2E8) : 0.f;
              }
            }
            lr[rt] += p[0] + p[1] + p[2] + p[3];
            f32x4 pv = {p[0], p[1], p[2], p[3]};
            *(bf16x4*)&Pw[l15 * 40 + hh2 * 16 + quad * 4] = __builtin_convertvector(pv, bf16x4);
          }
          // DS ops are wave-ordered; compiler emits lgkmcnt before pf's use
          const bf16x8 pf = *(const bf16x8*)&Pw[l15 * 40 + quad * 8];
#pragma unroll
          for (int vt = 0; vt < 4; ++vt)
            o[rt][vt] = __builtin_amdgcn_mfma_f32_16x16x32_bf16(pf, vf[vt], o[rt][vt], 0, 0, 0);
        }
      }
    }

    if (more) SCAT_V(b ^ 1);              // next buffer; next-iter barrier protects
  }

  // epilogue: total l per query, redistribute to output-row lanes, blend, store
  float lt[2];
#pragma unroll
  for (int rt = 0; rt < 2; ++rt) {
    float l = lr[rt];
    l += __shfl_xor(l, 16);
    l += __shfl_xor(l, 32);
    lt[rt] = l;                            // lanes sharing l15 hold total for q=R+l15
  }
#pragma unroll
  for (int rt = 0; rt < 2; ++rt)
#pragma unroll
    for (int i = 0; i < 4; ++i) {
      const float lq = __shfl(lt[rt], quad * 4 + i);
      const int qa = wq0 + rt * 16 + quad * 4 + i;
      const float w = (qa >= S - 128) ? (1.0f + (float)(qa - (S - 128)) * (1.0f / 127.0f)) : 1.0f;
      const float scl = w / lq;
#pragma unroll
      for (int vt = 0; vt < 4; ++vt)
        ((__bf16*)attnb)[(size_t)qa * D + h * HD + vt * 16 + l15] = (__bf16)(o[rt][vt][i] * scl);
    }
#undef LOAD_V
#undef SCAT_V
}

// ---------------- launch ----------------
extern "C" void kernel_launch(void* const* d_in, const int* in_sizes, int n_in,
                              void* d_out, int out_size, void* d_ws, size_t ws_size,
                              hipStream_t stream)
{
  const float* x  = (const float*)d_in[0];
  const float* Wq = (const float*)d_in[1];
  const float* Wk = (const float*)d_in[2];
  const float* Wv = (const float*)d_in[3];
  const float* Wo = (const float*)d_in[4];
  const float* bq = (const float*)d_in[5];
  const float* bk = (const float*)d_in[6];
  const float* bv = (const float*)d_in[7];
  const float* bo = (const float*)d_in[8];

  char* ws = (char*)d_ws;
  unsigned short* xb    = (unsigned short*)(ws);              // 16 MB
  unsigned short* wqkv  = (unsigned short*)(ws + 16777216);   //  6 MB
  unsigned short* wob   = (unsigned short*)(ws + 23068672);   //  2 MB
  float*          biasq = (float*)         (ws + 25165824);   // 12 KB
  unsigned short* qkv   = (unsigned short*)(ws + 25178112);   // 48 MB
  unsigned short* attnb = (unsigned short*)(ws + 75509760);   // 16 MB

  prep_kernel<<<2048, 256, 0, stream>>>((const float4*)x, (const float4*)Wq, (const float4*)Wk,
                                        (const float4*)Wv, (const float4*)Wo, (const float4*)bq,
                                        (const float4*)bk, (const float4*)bv,
                                        (ushort4*)xb, (ushort4*)wqkv, (ushort4*)wob, (float4*)biasq);

  gemm_nt<NQKV, true><<<dim3(64, 24), 256, 0, stream>>>(xb, wqkv, biasq, (void*)qkv, D);
  attn_fused<<<dim3(S / 128, H), 256, 0, stream>>>(qkv, attnb);
  gemm_nt<D, false><<<dim3(64, 8), 256, 0, stream>>>(attnb, wob, bo, d_out, D);
}

// Round 6
// 303.617 us; speedup vs baseline: 1.0237x; 1.0237x over previous
//
#include <hip/hip_runtime.h>

#define DEVI __device__ __forceinline__

constexpr int S = 8192, D = 1024, H = 16, HD = 64;
constexpr int NQKV = 3 * D;

typedef __attribute__((ext_vector_type(8))) __bf16 bf16x8;
typedef __attribute__((ext_vector_type(4))) __bf16 bf16x4;
typedef __attribute__((ext_vector_type(8))) unsigned short us8;
typedef __attribute__((ext_vector_type(4))) float f32x4;

DEVI unsigned short f2b(float f) {
  unsigned int u = __float_as_uint(f);
  u += 0x7fff + ((u >> 16) & 1);   // RNE
  return (unsigned short)(u >> 16);
}

DEVI ushort4 cvt4(float4 v) {
  ushort4 r; r.x = f2b(v.x); r.y = f2b(v.y); r.z = f2b(v.z); r.w = f2b(v.w); return r;
}

DEVI void load_lds16b(const void* g, void* l) {
  __builtin_amdgcn_global_load_lds((const __attribute__((address_space(1))) void*)g,
                                   (__attribute__((address_space(3))) void*)l,
                                   16, 0, 0);
}

// ---------------- prep: fp32 -> bf16 casts + weight/bias concat ----------------
__global__ void prep_kernel(const float4* __restrict__ x,
                            const float4* __restrict__ Wq, const float4* __restrict__ Wk,
                            const float4* __restrict__ Wv, const float4* __restrict__ Wo,
                            const float4* __restrict__ bq, const float4* __restrict__ bk,
                            const float4* __restrict__ bv,
                            ushort4* __restrict__ xb, ushort4* __restrict__ wqkv,
                            ushort4* __restrict__ wob, float4* __restrict__ biasq)
{
  constexpr int NX = S * D / 4;
  constexpr int NW = D * D / 4;
  constexpr int NB = D / 4;
  constexpr int TOT = NX + 4 * NW + 3 * NB;
  for (int i = blockIdx.x * blockDim.x + threadIdx.x; i < TOT; i += gridDim.x * blockDim.x) {
    if (i < NX) {
      xb[i] = cvt4(x[i]);
    } else if (i < NX + 3 * NW) {
      int j = i - NX;
      const float4* src = (j < NW) ? Wq : ((j < 2 * NW) ? Wk : Wv);
      int jj = (j < NW) ? j : ((j < 2 * NW) ? j - NW : j - 2 * NW);
      wqkv[j] = cvt4(src[jj]);
    } else if (i < NX + 4 * NW) {
      int j = i - NX - 3 * NW;
      wob[j] = cvt4(Wo[j]);
    } else {
      int j = i - NX - 4 * NW;
      const float4* src = (j < NB) ? bq : ((j < 2 * NB) ? bk : bv);
      int jj = (j < NB) ? j : ((j < 2 * NB) ? j - NB : j - 2 * NB);
      biasq[j] = src[jj];
    }
  }
}

// ---------------- NT GEMM: C[m][n] = sum_k A[m][k]*B[n][k] + bias[n] ----------------
template<int LDC, bool OUT_BF16>
__global__ __launch_bounds__(256)
void gemm_nt(const unsigned short* __restrict__ A,
             const unsigned short* __restrict__ B,
             const float* __restrict__ bias,
             void* __restrict__ C, int K)
{
  __shared__ __align__(16) unsigned short As[128 * 32];
  __shared__ __align__(16) unsigned short Bs[128 * 32];
  const int tid = threadIdx.x;
  const int wave = tid >> 6, lane = tid & 63;
  const int quad = lane >> 4, l15 = lane & 15;
  const int m0 = blockIdx.x * 128, n0 = blockIdx.y * 128;
  const int wr = wave >> 1, wc = wave & 1;

  const f32x4 fzero = {0.f, 0.f, 0.f, 0.f};
  f32x4 acc[4][4];
#pragma unroll
  for (int i = 0; i < 4; ++i)
#pragma unroll
    for (int j = 0; j < 4; ++j) acc[i][j] = fzero;

  const int segr = lane >> 2;
  const int cpst = lane & 3;

  for (int k0 = 0; k0 < K; k0 += 32) {
    __syncthreads();
#pragma unroll
    for (int j = 0; j < 4; ++j) {
      const int s = wave * 4 + j;
      const int s7 = s & 7;
      const int r = s7 * 16 + segr;
      const int c = cpst ^ ((r >> 1) & 3);
      const unsigned short* g = (s < 8)
        ? A + (size_t)(m0 + r) * K + k0 + c * 8
        : B + (size_t)(n0 + r) * K + k0 + c * 8;
      unsigned short* l = ((s < 8) ? As : Bs) + s7 * 512;
      load_lds16b(g, l);
    }
    __syncthreads();

    bf16x8 af[4], bfr[4];
#pragma unroll
    for (int it = 0; it < 4; ++it) {
      const int r = wr * 64 + it * 16 + l15;
      const int cp = quad ^ ((r >> 1) & 3);
      af[it] = *(const bf16x8*)&As[r * 32 + cp * 8];
    }
#pragma unroll
    for (int jt = 0; jt < 4; ++jt) {
      const int r = wc * 64 + jt * 16 + l15;
      const int cp = quad ^ ((r >> 1) & 3);
      bfr[jt] = *(const bf16x8*)&Bs[r * 32 + cp * 8];
    }
#pragma unroll
    for (int it = 0; it < 4; ++it)
#pragma unroll
      for (int jt = 0; jt < 4; ++jt)
        acc[it][jt] = __builtin_amdgcn_mfma_f32_16x16x32_bf16(af[it], bfr[jt], acc[it][jt], 0, 0, 0);
  }

#pragma unroll
  for (int it = 0; it < 4; ++it)
#pragma unroll
    for (int jt = 0; jt < 4; ++jt) {
      const int col = n0 + wc * 64 + jt * 16 + l15;
      const float bv = bias[col];
#pragma unroll
      for (int i = 0; i < 4; ++i) {
        const int row = m0 + wr * 64 + it * 16 + quad * 4 + i;
        const float v = acc[it][jt][i] + bv;
        if constexpr (OUT_BF16)
          ((unsigned short*)C)[(size_t)row * LDC + col] = f2b(v);
        else
          ((float*)C)[(size_t)row * LDC + col] = v;
      }
    }
}

// ---------------- transpose V: qkv[key][2048+h*64+d] -> vtb[h][d][key] ----------------
__global__ __launch_bounds__(256)
void transpose_v(const unsigned short* __restrict__ qkv, unsigned short* __restrict__ vtb)
{
  __shared__ unsigned short T[64 * 72];
  const int tid = threadIdx.x;
  const int kb = blockIdx.x, h = blockIdx.y;
  const unsigned short* Vp = qkv + 2 * D + h * HD;
  const int key = tid >> 3, sg = tid & 7;
#pragma unroll
  for (int r = 0; r < 2; ++r) {
    us8 v = *(const us8*)(Vp + (size_t)(kb * 64 + key + r * 32) * NQKV + sg * 8);
    unsigned short* dst = &T[sg * 8 * 72 + key + r * 32];
#pragma unroll
    for (int j = 0; j < 8; ++j) dst[j * 72] = v[j];
  }
  __syncthreads();
  const int d = tid >> 2, kc = tid & 3;
  us8* outp = (us8*)(vtb + (size_t)h * HD * S + (size_t)d * S + kb * 64 + kc * 16);
  outp[0] = *(const us8*)&T[d * 72 + kc * 16];
  outp[1] = *(const us8*)&T[d * 72 + kc * 16 + 8];
}

// ---------------- fused sliding-window attention (v6) ----------------
// K and V^T both staged via conflict-free-gather global_load_lds DMA, double-
// buffered, ONE barrier/tile. Phase-split: all QK->exp->P writes (per-rt P
// buffers, independent chains), then all PV. No-max exp2 softmax.
__global__ __launch_bounds__(256)
void attn_fused(const unsigned short* __restrict__ qkv,
                const unsigned short* __restrict__ vtb,
                unsigned short* __restrict__ attnb)
{
  __shared__ __align__(16) unsigned short Ks[2][64 * 64];   // [key][(dc^(key&7))*8+..]
  __shared__ __align__(16) unsigned short Vt[2][64 * 64];   // [d][(kc^(d&7))*8+..]
  __shared__ __align__(16) unsigned short Ps[4][2][16 * 72];// [wave][rt][q][key], pitch 72
  const int tid = threadIdx.x;
  const int wave = tid >> 6, lane = tid & 63;
  const int quad = lane >> 4, l15 = lane & 15;
  const int h = blockIdx.y;
  const int q0 = blockIdx.x * 128;
  const int wq0 = q0 + wave * 32;

  const unsigned short* Qp = qkv + h * HD;
  const unsigned short* Kp = qkv + D + h * HD;
  const unsigned short* Vh = vtb + (size_t)h * HD * S;   // [d][key]

  bf16x8 qf[2][2];
#pragma unroll
  for (int rt = 0; rt < 2; ++rt)
#pragma unroll
    for (int ksp = 0; ksp < 2; ++ksp)
      qf[rt][ksp] = *(const bf16x8*)(Qp + (size_t)(wq0 + rt * 16 + l15) * NQKV + ksp * 32 + quad * 8);

  const f32x4 fzero = {0.f, 0.f, 0.f, 0.f};
  f32x4 o[2][4];
  float lr[2] = {0.f, 0.f};
#pragma unroll
  for (int rt = 0; rt < 2; ++rt)
#pragma unroll
    for (int vt2 = 0; vt2 < 4; ++vt2) o[rt][vt2] = fzero;

  const int ks = (q0 >= 512) ? (q0 - 512) : 0;
  const int ke = (q0 + 640 < S) ? (q0 + 640) : S;

  // DMA gather roles: slot s = tid + r*256 (lane-linear LDS dest)
  const int srow = tid >> 3;            // K: key 0..31 ; V: d 0..31 (r adds 32)
  const int sg   = tid & 7;
  const int scol = sg ^ (srow & 7);     // swizzled 8-elem chunk index

#define STAGE(kt_, b_)                                                            \
  {                                                                               \
    _Pragma("unroll")                                                             \
    for (int r = 0; r < 2; ++r) {                                                 \
      load_lds16b(Kp + (size_t)((kt_) + srow + r * 32) * NQKV + scol * 8,         \
                  &Ks[b_][(size_t)tid * 8 + r * 2048]);                           \
      load_lds16b(Vh + (size_t)(srow + r * 32) * S + (kt_) + scol * 8,            \
                  &Vt[b_][(size_t)tid * 8 + r * 2048]);                           \
    }                                                                             \
  }

  STAGE(ks, 0);

  constexpr float L2E8 = 0.18033688011112042f;  // log2(e)/8

  int b = 0;
  for (int kt = ks; kt < ke; kt += 64, b ^= 1) {
    __syncthreads();                       // drains DMA for buf b
    if (kt + 64 < ke) STAGE(kt + 64, b ^ 1);   // overlaps compute below

    if (kt + 63 >= wq0 - 512 && kt <= wq0 + 542) {
      // K fragments for the whole 64-key tile (8 x b128, <=2-way)
      bf16x8 kf[4][2];
#pragma unroll
      for (int hh = 0; hh < 4; ++hh)
#pragma unroll
        for (int ksp = 0; ksp < 2; ++ksp)
          kf[hh][ksp] = *(const bf16x8*)&Ks[b][(hh * 16 + l15) * 64
                                              + ((ksp * 4 + quad) ^ (l15 & 7)) * 8];

      // ---- Phase A: QK^T (S^T form), exp, P writes (4 independent chains) ----
#pragma unroll
      for (int st = 0; st < 2; ++st) {
        const int C0 = kt + st * 32;
#pragma unroll
        for (int rt = 0; rt < 2; ++rt) {
          const int R = wq0 + rt * 16;
          if (!((C0 + 31 >= R - 512) && (C0 <= R + 526))) continue;
          const int qa = R + l15;
          unsigned short* Pw = (unsigned short*)Ps[wave][rt];
#pragma unroll
          for (int hh2 = 0; hh2 < 2; ++hh2) {
            const int hh = st * 2 + hh2;
            const int C = C0 + hh2 * 16;
            const bool any  = (C + 15 >= R - 512) && (C <= R + 526);
            const bool full = (C >= R - 497) && (C <= R + 496);
            float p[4];
            if (!any) {
              p[0] = p[1] = p[2] = p[3] = 0.f;
            } else {
              f32x4 z0 = fzero, z1 = fzero;
              z0 = __builtin_amdgcn_mfma_f32_16x16x32_bf16(kf[hh][0], qf[rt][0], z0, 0, 0, 0);
              z1 = __builtin_amdgcn_mfma_f32_16x16x32_bf16(kf[hh][1], qf[rt][1], z1, 0, 0, 0);
              const f32x4 z = z0 + z1;
              if (full) {
#pragma unroll
                for (int i = 0; i < 4; ++i) p[i] = __builtin_amdgcn_exp2f(z[i] * L2E8);
              } else {
                const int base = C + quad * 4 - qa + 512;
#pragma unroll
                for (int i = 0; i < 4; ++i)
                  p[i] = ((unsigned)(base + i) < 1024u) ? __builtin_amdgcn_exp2f(z[i] * L2E8) : 0.f;
              }
            }
            lr[rt] += p[0] + p[1] + p[2] + p[3];
            f32x4 pv = {p[0], p[1], p[2], p[3]};
            *(bf16x4*)&Pw[l15 * 72 + hh * 16 + quad * 4] = __builtin_convertvector(pv, bf16x4);
          }
        }
      }

      // ---- Phase B: PV (wave-ordered DS => pf reads see all P writes) ----
#pragma unroll
      for (int st = 0; st < 2; ++st) {
        const int C0 = kt + st * 32;
        if (!((C0 + 31 >= wq0 - 512) && (C0 <= wq0 + 542))) continue;
        bf16x8 vf[4];
#pragma unroll
        for (int vt2 = 0; vt2 < 4; ++vt2) {
          const int d = vt2 * 16 + l15;
          vf[vt2] = *(const bf16x8*)&Vt[b][d * 64 + (((st * 4 + quad) ^ (d & 7))) * 8];
        }
#pragma unroll
        for (int rt = 0; rt < 2; ++rt) {
          const int R = wq0 + rt * 16;
          if (!((C0 + 31 >= R - 512) && (C0 <= R + 526))) continue;
          const bf16x8 pf = *(const bf16x8*)&Ps[wave][rt][l15 * 72 + (st * 4 + quad) * 8];
#pragma unroll
          for (int vt2 = 0; vt2 < 4; ++vt2)
            o[rt][vt2] = __builtin_amdgcn_mfma_f32_16x16x32_bf16(pf, vf[vt2], o[rt][vt2], 0, 0, 0);
        }
      }
    }
  }

  // epilogue: total l per query, redistribute, tail blend, store
  float lt[2];
#pragma unroll
  for (int rt = 0; rt < 2; ++rt) {
    float l = lr[rt];
    l += __shfl_xor(l, 16);
    l += __shfl_xor(l, 32);
    lt[rt] = l;
  }
#pragma unroll
  for (int rt = 0; rt < 2; ++rt)
#pragma unroll
    for (int i = 0; i < 4; ++i) {
      const float lq = __shfl(lt[rt], quad * 4 + i);
      const int qa = wq0 + rt * 16 + quad * 4 + i;
      const float w = (qa >= S - 128) ? (1.0f + (float)(qa - (S - 128)) * (1.0f / 127.0f)) : 1.0f;
      const float scl = w / lq;
#pragma unroll
      for (int vt2 = 0; vt2 < 4; ++vt2)
        ((__bf16*)attnb)[(size_t)qa * D + h * HD + vt2 * 16 + l15] = (__bf16)(o[rt][vt2][i] * scl);
    }
#undef STAGE
}

// ---------------- launch ----------------
extern "C" void kernel_launch(void* const* d_in, const int* in_sizes, int n_in,
                              void* d_out, int out_size, void* d_ws, size_t ws_size,
                              hipStream_t stream)
{
  const float* x  = (const float*)d_in[0];
  const float* Wq = (const float*)d_in[1];
  const float* Wk = (const float*)d_in[2];
  const float* Wv = (const float*)d_in[3];
  const float* Wo = (const float*)d_in[4];
  const float* bq = (const float*)d_in[5];
  const float* bk = (const float*)d_in[6];
  const float* bv = (const float*)d_in[7];
  const float* bo = (const float*)d_in[8];

  char* ws = (char*)d_ws;
  unsigned short* xb    = (unsigned short*)(ws);              // 16 MB (reused as vtb after QKV GEMM)
  unsigned short* wqkv  = (unsigned short*)(ws + 16777216);   //  6 MB
  unsigned short* wob   = (unsigned short*)(ws + 23068672);   //  2 MB
  float*          biasq = (float*)         (ws + 25165824);   // 12 KB
  unsigned short* qkv   = (unsigned short*)(ws + 25178112);   // 48 MB
  unsigned short* attnb = (unsigned short*)(ws + 75509760);   // 16 MB
  unsigned short* vtb   = xb;                                 // alias: xb is dead after QKV GEMM

  prep_kernel<<<2048, 256, 0, stream>>>((const float4*)x, (const float4*)Wq, (const float4*)Wk,
                                        (const float4*)Wv, (const float4*)Wo, (const float4*)bq,
                                        (const float4*)bk, (const float4*)bv,
                                        (ushort4*)xb, (ushort4*)wqkv, (ushort4*)wob, (float4*)biasq);

  gemm_nt<NQKV, true><<<dim3(64, 24), 256, 0, stream>>>(xb, wqkv, biasq, (void*)qkv, D);
  transpose_v<<<dim3(S / 64, H), 256, 0, stream>>>(qkv, vtb);
  attn_fused<<<dim3(S / 128, H), 256, 0, stream>>>(qkv, vtb, attnb);
  gemm_nt<D, false><<<dim3(64, 8), 256, 0, stream>>>(attnb, wob, bo, d_out, D);
}

// Round 7
// 274.106 us; speedup vs baseline: 1.1340x; 1.1077x over previous
//
#include <hip/hip_runtime.h>

#define DEVI __device__ __forceinline__

constexpr int S = 8192, D = 1024, H = 16, HD = 64;
constexpr int NQKV = 3 * D;

typedef __attribute__((ext_vector_type(8))) __bf16 bf16x8;
typedef __attribute__((ext_vector_type(4))) __bf16 bf16x4;
typedef __attribute__((ext_vector_type(8))) unsigned short us8;
typedef __attribute__((ext_vector_type(4))) float f32x4;
typedef __attribute__((ext_vector_type(16))) float f32x16;

DEVI unsigned short f2b(float f) {
  unsigned int u = __float_as_uint(f);
  u += 0x7fff + ((u >> 16) & 1);   // RNE
  return (unsigned short)(u >> 16);
}

DEVI ushort4 cvt4(float4 v) {
  ushort4 r; r.x = f2b(v.x); r.y = f2b(v.y); r.z = f2b(v.z); r.w = f2b(v.w); return r;
}

DEVI void load_lds16b(const void* g, void* l) {
  __builtin_amdgcn_global_load_lds((const __attribute__((address_space(1))) void*)g,
                                   (__attribute__((address_space(3))) void*)l,
                                   16, 0, 0);
}

// ---------------- prep: fp32 -> bf16 casts + weight/bias concat ----------------
__global__ void prep_kernel(const float4* __restrict__ x,
                            const float4* __restrict__ Wq, const float4* __restrict__ Wk,
                            const float4* __restrict__ Wv, const float4* __restrict__ Wo,
                            const float4* __restrict__ bq, const float4* __restrict__ bk,
                            const float4* __restrict__ bv,
                            ushort4* __restrict__ xb, ushort4* __restrict__ wqkv,
                            ushort4* __restrict__ wob, float4* __restrict__ biasq)
{
  constexpr int NX = S * D / 4;
  constexpr int NW = D * D / 4;
  constexpr int NB = D / 4;
  constexpr int TOT = NX + 4 * NW + 3 * NB;
  for (int i = blockIdx.x * blockDim.x + threadIdx.x; i < TOT; i += gridDim.x * blockDim.x) {
    if (i < NX) {
      xb[i] = cvt4(x[i]);
    } else if (i < NX + 3 * NW) {
      int j = i - NX;
      const float4* src = (j < NW) ? Wq : ((j < 2 * NW) ? Wk : Wv);
      int jj = (j < NW) ? j : ((j < 2 * NW) ? j - NW : j - 2 * NW);
      wqkv[j] = cvt4(src[jj]);
    } else if (i < NX + 4 * NW) {
      int j = i - NX - 3 * NW;
      wob[j] = cvt4(Wo[j]);
    } else {
      int j = i - NX - 4 * NW;
      const float4* src = (j < NB) ? bq : ((j < 2 * NB) ? bk : bv);
      int jj = (j < NB) ? j : ((j < 2 * NB) ? j - NB : j - 2 * NB);
      biasq[j] = src[jj];
    }
  }
}

// ---------------- NT GEMM: C[m][n] = sum_k A[m][k]*B[n][k] + bias[n] ----------------
// v7: double-buffered LDS, ONE barrier per BK=32 iteration; DMA of tile k+1
// overlaps MFMA on tile k.
template<int LDC, bool OUT_BF16>
__global__ __launch_bounds__(256)
void gemm_nt(const unsigned short* __restrict__ A,
             const unsigned short* __restrict__ B,
             const float* __restrict__ bias,
             void* __restrict__ C, int K)
{
  __shared__ __align__(16) unsigned short As[2][128 * 32];
  __shared__ __align__(16) unsigned short Bs[2][128 * 32];
  const int tid = threadIdx.x;
  const int wave = tid >> 6, lane = tid & 63;
  const int quad = lane >> 4, l15 = lane & 15;
  const int m0 = blockIdx.x * 128, n0 = blockIdx.y * 128;
  const int wr = wave >> 1, wc = wave & 1;

  const f32x4 fzero = {0.f, 0.f, 0.f, 0.f};
  f32x4 acc[4][4];
#pragma unroll
  for (int i = 0; i < 4; ++i)
#pragma unroll
    for (int j = 0; j < 4; ++j) acc[i][j] = fzero;

  const int segr = lane >> 2;
  const int cpst = lane & 3;

#define GST(k0_, b_)                                                              \
  {                                                                               \
    _Pragma("unroll")                                                             \
    for (int j = 0; j < 4; ++j) {                                                 \
      const int s = wave * 4 + j;                                                 \
      const int s7 = s & 7;                                                       \
      const int r = s7 * 16 + segr;                                               \
      const int c = cpst ^ ((r >> 1) & 3);                                        \
      const unsigned short* g = (s < 8)                                           \
        ? A + (size_t)(m0 + r) * K + (k0_) + c * 8                                \
        : B + (size_t)(n0 + r) * K + (k0_) + c * 8;                               \
      unsigned short* l = ((s < 8) ? As[b_] : Bs[b_]) + s7 * 512;                 \
      load_lds16b(g, l);                                                          \
    }                                                                             \
  }

  GST(0, 0);
  int b = 0;
  for (int k0 = 0; k0 < K; k0 += 32, b ^= 1) {
    __syncthreads();
    if (k0 + 32 < K) GST(k0 + 32, b ^ 1);

    bf16x8 af[4], bfr[4];
#pragma unroll
    for (int it = 0; it < 4; ++it) {
      const int r = wr * 64 + it * 16 + l15;
      const int cp = quad ^ ((r >> 1) & 3);
      af[it] = *(const bf16x8*)&As[b][r * 32 + cp * 8];
    }
#pragma unroll
    for (int jt = 0; jt < 4; ++jt) {
      const int r = wc * 64 + jt * 16 + l15;
      const int cp = quad ^ ((r >> 1) & 3);
      bfr[jt] = *(const bf16x8*)&Bs[b][r * 32 + cp * 8];
    }
#pragma unroll
    for (int it = 0; it < 4; ++it)
#pragma unroll
      for (int jt = 0; jt < 4; ++jt)
        acc[it][jt] = __builtin_amdgcn_mfma_f32_16x16x32_bf16(af[it], bfr[jt], acc[it][jt], 0, 0, 0);
  }
#undef GST

#pragma unroll
  for (int it = 0; it < 4; ++it)
#pragma unroll
    for (int jt = 0; jt < 4; ++jt) {
      const int col = n0 + wc * 64 + jt * 16 + l15;
      const float bv = bias[col];
#pragma unroll
      for (int i = 0; i < 4; ++i) {
        const int row = m0 + wr * 64 + it * 16 + quad * 4 + i;
        const float v = acc[it][jt][i] + bv;
        if constexpr (OUT_BF16)
          ((unsigned short*)C)[(size_t)row * LDC + col] = f2b(v);
        else
          ((float*)C)[(size_t)row * LDC + col] = v;
      }
    }
}

// ---------------- transpose V: qkv[key][2048+h*64+d] -> vtb[h][d][key] ----------------
__global__ __launch_bounds__(256)
void transpose_v(const unsigned short* __restrict__ qkv, unsigned short* __restrict__ vtb)
{
  __shared__ unsigned short T[64 * 72];
  const int tid = threadIdx.x;
  const int kb = blockIdx.x, h = blockIdx.y;
  const unsigned short* Vp = qkv + 2 * D + h * HD;
  const int key = tid >> 3, sg = tid & 7;
#pragma unroll
  for (int r = 0; r < 2; ++r) {
    us8 v = *(const us8*)(Vp + (size_t)(kb * 64 + key + r * 32) * NQKV + sg * 8);
    unsigned short* dst = &T[sg * 8 * 72 + key + r * 32];
#pragma unroll
    for (int j = 0; j < 8; ++j) dst[j * 72] = v[j];
  }
  __syncthreads();
  const int d = tid >> 2, kc = tid & 3;
  us8* outp = (us8*)(vtb + (size_t)h * HD * S + (size_t)d * S + kb * 64 + kc * 16);
  outp[0] = *(const us8*)&T[d * 72 + kc * 16];
  outp[1] = *(const us8*)&T[d * 72 + kc * 16 + 8];
}

// ---------------- fused sliding-window attention (v7, 32x32x16 MFMA) ----------------
// One wave = 32 queries. S^T = mfma32(K,Q) over kdim (4 MFMAs), exp, P -> LDS
// (chunk-XOR pitch-64), PV = mfma32(P,V^T) (8 MFMAs). K/V^T staged via DMA,
// double-buffered, one barrier/tile. XCD swizzle: 2 heads per XCD group.
__global__ __launch_bounds__(256)
void attn_fused(const unsigned short* __restrict__ qkv,
                const unsigned short* __restrict__ vtb,
                unsigned short* __restrict__ attnb)
{
  __shared__ __align__(16) unsigned short Ks[2][64 * 64];   // [key][slot], slot = dc ^ (key&7)
  __shared__ __align__(16) unsigned short Vt[2][64 * 64];   // [d][slot],  slot = kc ^ (d&7)
  __shared__ __align__(16) unsigned short Ps[4][32 * 64];   // per-wave [q][slot], slot = p8 ^ (q&7)
  const int tid = threadIdx.x;
  const int wave = tid >> 6, lane = tid & 63;
  const int l31 = lane & 31, hi = lane >> 5;

  // XCD swizzle: assume xcd = linear_block_id % 8; give each XCD 2 heads x all q.
  const int id = blockIdx.x + 64 * blockIdx.y;        // 0..1023
  const int h  = (id & 7) * 2 + ((id >> 3) >> 6);
  const int q0 = ((id >> 3) & 63) * 128;
  const int wq0 = q0 + wave * 32;

  const unsigned short* Qp = qkv + h * HD;
  const unsigned short* Kp = qkv + D + h * HD;
  const unsigned short* Vh = vtb + (size_t)h * HD * S;   // [d][key]

  // Q fragments (B-operand): lane holds Q[q=l31][m*16 + hi*8 + j]
  bf16x8 qf[4];
#pragma unroll
  for (int m = 0; m < 4; ++m)
    qf[m] = *(const bf16x8*)(Qp + (size_t)(wq0 + l31) * NQKV + m * 16 + hi * 8);

  f32x16 o[2];
#pragma unroll
  for (int n = 0; n < 2; ++n)
#pragma unroll
    for (int r = 0; r < 16; ++r) o[n][r] = 0.f;
  float lr = 0.f;

  const int ks = (q0 >= 512) ? (q0 - 512) : 0;
  const int ke = (q0 + 640 < S) ? (q0 + 640) : S;

  // DMA gather roles
  const int srow = tid >> 3;            // 0..31 (+32 via r)
  const int sg   = tid & 7;
  const int scol = sg ^ (srow & 7);

#define STAGE(kt_, b_)                                                            \
  {                                                                               \
    _Pragma("unroll")                                                             \
    for (int r = 0; r < 2; ++r) {                                                 \
      load_lds16b(Kp + (size_t)((kt_) + srow + r * 32) * NQKV + scol * 8,         \
                  &Ks[b_][(size_t)tid * 8 + r * 2048]);                           \
      load_lds16b(Vh + (size_t)(srow + r * 32) * S + (kt_) + scol * 8,            \
                  &Vt[b_][(size_t)tid * 8 + r * 2048]);                           \
    }                                                                             \
  }

  STAGE(ks, 0);

  constexpr float L2E8 = 0.18033688011112042f;  // log2(e)/8

  int b = 0;
  for (int kt = ks; kt < ke; kt += 64, b ^= 1) {
    __syncthreads();
    if (kt + 64 < ke) STAGE(kt + 64, b ^ 1);

    if (kt + 63 >= wq0 - 512 && kt <= wq0 + 31 + 511) {
      unsigned short* Pw = (unsigned short*)Ps[wave];

      // ---- Phase A: S^T = K·Q^T (32 keys x 32 queries per kb2), exp, P write ----
#pragma unroll
      for (int kb2 = 0; kb2 < 2; ++kb2) {
        const int C0 = kt + kb2 * 32;
        const bool any = (C0 + 31 >= wq0 - 512) && (C0 <= wq0 + 31 + 511);
        float p[16];
        if (!any) {
#pragma unroll
          for (int r = 0; r < 16; ++r) p[r] = 0.f;
        } else {
          bf16x8 kf[4];
#pragma unroll
          for (int m = 0; m < 4; ++m)
            kf[m] = *(const bf16x8*)&Ks[b][(kb2 * 32 + l31) * 64 + ((m * 2 + hi) ^ (l31 & 7)) * 8];
          f32x16 z;
#pragma unroll
          for (int r = 0; r < 16; ++r) z[r] = 0.f;
#pragma unroll
          for (int m = 0; m < 4; ++m)
            z = __builtin_amdgcn_mfma_f32_32x32x16_bf16(kf[m], qf[m], z, 0, 0, 0);

          const bool full = (C0 >= wq0 - 481) && (C0 <= wq0 + 480);
          if (full) {
#pragma unroll
            for (int r = 0; r < 16; ++r) p[r] = __builtin_amdgcn_exp2f(z[r] * L2E8);
          } else {
            // key = C0 + (r&3) + 8*(r>>2) + 4*hi ; q = wq0 + l31
            const int base = C0 + 4 * hi - (wq0 + l31) + 512;
#pragma unroll
            for (int r = 0; r < 16; ++r) {
              const int u = base + (r & 3) + 8 * (r >> 2);
              p[r] = ((unsigned)u < 1024u) ? __builtin_amdgcn_exp2f(z[r] * L2E8) : 0.f;
            }
          }
        }
#pragma unroll
        for (int r = 0; r < 16; ++r) lr += p[r];
        // write 4 groups of 4 consecutive keys: rows g*8 + hi*4 + (0..3)
#pragma unroll
        for (int g = 0; g < 4; ++g) {
          f32x4 pv = {p[g * 4], p[g * 4 + 1], p[g * 4 + 2], p[g * 4 + 3]};
          const int p8 = kb2 * 4 + g;
          *(bf16x4*)&Pw[l31 * 64 + (p8 ^ (l31 & 7)) * 8 + hi * 4] = __builtin_convertvector(pv, bf16x4);
        }
      }

      // ---- Phase B: O += P·V (A from Ps, B from Vt) ----
      bf16x8 pf[4];
#pragma unroll
      for (int s = 0; s < 4; ++s)
        pf[s] = *(const bf16x8*)&Pw[l31 * 64 + ((s * 2 + hi) ^ (l31 & 7)) * 8];
#pragma unroll
      for (int n = 0; n < 2; ++n)
#pragma unroll
        for (int s = 0; s < 4; ++s) {
          const int d = n * 32 + l31;
          const bf16x8 vf = *(const bf16x8*)&Vt[b][d * 64 + ((s * 2 + hi) ^ (l31 & 7)) * 8];
          o[n] = __builtin_amdgcn_mfma_f32_32x32x16_bf16(pf[s], vf, o[n], 0, 0, 0);
        }
    }
  }
#undef STAGE

  // epilogue: fold l across hi halves (each lane covers 16 of 32 keys-rows for q=l31)
  lr += __shfl_xor(lr, 32);
#pragma unroll
  for (int r = 0; r < 16; ++r) {
    const int qr = (r & 3) + 8 * (r >> 2) + 4 * hi;
    const float lq = __shfl(lr, qr);           // lane qr holds l(q = wq0+qr)
    const int qa = wq0 + qr;
    const float w = (qa >= S - 128) ? (1.0f + (float)(qa - (S - 128)) * (1.0f / 127.0f)) : 1.0f;
    const float scl = w / lq;
#pragma unroll
    for (int n = 0; n < 2; ++n)
      ((__bf16*)attnb)[(size_t)qa * D + h * HD + n * 32 + l31] = (__bf16)(o[n][r] * scl);
  }
}

// ---------------- launch ----------------
extern "C" void kernel_launch(void* const* d_in, const int* in_sizes, int n_in,
                              void* d_out, int out_size, void* d_ws, size_t ws_size,
                              hipStream_t stream)
{
  const float* x  = (const float*)d_in[0];
  const float* Wq = (const float*)d_in[1];
  const float* Wk = (const float*)d_in[2];
  const float* Wv = (const float*)d_in[3];
  const float* Wo = (const float*)d_in[4];
  const float* bq = (const float*)d_in[5];
  const float* bk = (const float*)d_in[6];
  const float* bv = (const float*)d_in[7];
  const float* bo = (const float*)d_in[8];

  char* ws = (char*)d_ws;
  unsigned short* xb    = (unsigned short*)(ws);              // 16 MB (reused as vtb)
  unsigned short* wqkv  = (unsigned short*)(ws + 16777216);   //  6 MB
  unsigned short* wob   = (unsigned short*)(ws + 23068672);   //  2 MB
  float*          biasq = (float*)         (ws + 25165824);   // 12 KB
  unsigned short* qkv   = (unsigned short*)(ws + 25178112);   // 48 MB
  unsigned short* attnb = (unsigned short*)(ws + 75509760);   // 16 MB
  unsigned short* vtb   = xb;                                 // xb dead after QKV GEMM

  prep_kernel<<<2048, 256, 0, stream>>>((const float4*)x, (const float4*)Wq, (const float4*)Wk,
                                        (const float4*)Wv, (const float4*)Wo, (const float4*)bq,
                                        (const float4*)bk, (const float4*)bv,
                                        (ushort4*)xb, (ushort4*)wqkv, (ushort4*)wob, (float4*)biasq);

  gemm_nt<NQKV, true><<<dim3(64, 24), 256, 0, stream>>>(xb, wqkv, biasq, (void*)qkv, D);
  transpose_v<<<dim3(S / 64, H), 256, 0, stream>>>(qkv, vtb);
  attn_fused<<<dim3(S / 128, H), 256, 0, stream>>>(qkv, vtb, attnb);
  gemm_nt<D, false><<<dim3(64, 8), 256, 0, stream>>>(attnb, wob, bo, d_out, D);
}